// Round 12
// baseline (500.876 us; speedup 1.0000x reference)
//
#include <hip/hip_runtime.h>
#include <hip/hip_bf16.h>

// ---------------------------------------------------------------------------
// GATv2 (2 conv + GraphNorm + MLP) on MI355X.
// Round 12: dispatch-count reduction — prep_all fuses cast + 6 transposes +
// zeroing (8 launches -> 1); colstats_fused folds norm_finalize via the
// last-block-done pattern (removes 2 zero + 2 finalize launches).
// Aggregate / GEMM / scan logic unchanged from round 11.
// ---------------------------------------------------------------------------

typedef __bf16 bf16x8 __attribute__((ext_vector_type(8)));
typedef float  f32x4  __attribute__((ext_vector_type(4)));

__device__ __forceinline__ unsigned short f2b(float f) {   // RNE f32->bf16
    unsigned u = __float_as_uint(f);
    return (unsigned short)((u + 0x7fffu + ((u >> 16) & 1u)) >> 16);
}

// ----------------------------- fused prep ----------------------------------
// Segments: [zero s_sum/s_sq (512 f)] [zero hist (n i32)] [cast x (nx4 u4)]
// [T c0_wl 32768] [T c0_wr 32768] [T c1_wl 65536] [T c1_wr 65536]
// [T lin0 16384] [T lin1 4096]; thread 0 zeroes the done-counter.
__global__ __launch_bounds__(256) void prep_all(
    const float* __restrict__ x, unsigned short* __restrict__ xbf, int nx4,
    const float* __restrict__ w0l, const float* __restrict__ w0r, unsigned short* __restrict__ Wt0,
    const float* __restrict__ w1l, const float* __restrict__ w1r, unsigned short* __restrict__ Wt1,
    const float* __restrict__ l0, unsigned short* __restrict__ Lt0,
    const float* __restrict__ l1, unsigned short* __restrict__ Lt1,
    float* __restrict__ zf, int* __restrict__ hist, int nh, int* __restrict__ counter)
{
    int t = blockIdx.x * 256 + threadIdx.x;
    if (t == 0) *counter = 0;
    if (t < 512) { zf[t] = 0.f; }
    int i = t - 512;
    if (i >= 0 && i < nh) hist[i] = 0;
    i -= nh;
    if (i >= 0 && i < nx4) {
        float4 v = ((const float4*)x)[i];
        ushort4 o = { f2b(v.x), f2b(v.y), f2b(v.z), f2b(v.w) };
        ((ushort4*)xbf)[i] = o;
    }
    i -= nx4;
    if (i >= 0 && i < 32768) { int nn = i >> 7, kk = i & 127; Wt0[i] = f2b(w0l[kk * 256 + nn]); }
    i -= 32768;
    if (i >= 0 && i < 32768) { int nn = i >> 7, kk = i & 127; Wt0[32768 + i] = f2b(w0r[kk * 256 + nn]); }
    i -= 32768;
    if (i >= 0 && i < 65536) { int nn = i >> 8, kk = i & 255; Wt1[i] = f2b(w1l[kk * 256 + nn]); }
    i -= 65536;
    if (i >= 0 && i < 65536) { int nn = i >> 8, kk = i & 255; Wt1[65536 + i] = f2b(w1r[kk * 256 + nn]); }
    i -= 65536;
    if (i >= 0 && i < 16384) { int nn = i >> 8, kk = i & 255; Lt0[i] = f2b(l0[kk * 64 + nn]); }
    i -= 16384;
    if (i >= 0 && i < 4096)  { int nn = i >> 6, kk = i & 63;  Lt1[i] = f2b(l1[kk * 64 + nn]); }
}

// ----------------------------- MFMA GEMM -----------------------------------
// C[M,N](bf16) = act(A[M,K](bf16) @ Bt[N,K]^T(bf16) + bias); K compile-time.
// Block: 4 waves, tile 256(M)x64(N); wave w owns rows [w*64, w*64+64).
template<int K, bool RELU>
__global__ __launch_bounds__(256) void mfma_gemm(
    const unsigned short* __restrict__ A, const unsigned short* __restrict__ Bt,
    const float* __restrict__ bias0, const float* __restrict__ bias1, int split,
    unsigned short* __restrict__ C, int M, int N, int nt)
{
    // XCD-bijective swizzle of flat block id (m204 formula)
    const int nwg = gridDim.x;
    const int bid = blockIdx.x;
    const int q = nwg >> 3, r = nwg & 7;
    const int xcd = bid & 7, pos = bid >> 3;
    const int wgid = (xcd < r ? xcd * (q + 1) : r * (q + 1) + (xcd - r) * q) + pos;
    const int tm = wgid / nt;            // M-tile (flat is M-fast within chunk)
    const int tn = wgid - tm * nt;       // N-tile

    const int lane = threadIdx.x & 63;
    const int w = threadIdx.x >> 6;
    const int bm = tm * 256 + w * 64;
    const int bn = tn * 64;
    const int lr = lane & 15;
    const int g  = lane >> 4;
    const int lk = g * 8;

    f32x4 acc[4][4] = {};
    const unsigned short* pa[4];
    #pragma unroll
    for (int mi = 0; mi < 4; ++mi) {
        int rr = bm + mi * 16 + lr;
        if (rr >= M) rr = M - 1;         // clamp (writes are guarded)
        pa[mi] = A + (size_t)rr * K + lk;
    }
    const unsigned short* pb = Bt + (size_t)(bn + lr) * K + lk;

    #pragma unroll
    for (int k0 = 0; k0 < K; k0 += 32) {
        bf16x8 bfr[4], afr[4];
        #pragma unroll
        for (int ni = 0; ni < 4; ++ni)
            bfr[ni] = *(const bf16x8*)(pb + (size_t)ni * 16 * K + k0);
        #pragma unroll
        for (int mi = 0; mi < 4; ++mi)
            afr[mi] = *(const bf16x8*)(pa[mi] + k0);
        #pragma unroll
        for (int mi = 0; mi < 4; ++mi)
            #pragma unroll
            for (int ni = 0; ni < 4; ++ni)
                acc[mi][ni] = __builtin_amdgcn_mfma_f32_16x16x32_bf16(
                    bfr[ni], afr[mi], acc[mi][ni], 0, 0, 0);
    }

    // epilogue: lane holds C[bm+mi*16+lr][bn+ni*16+g*4 .. +3]
    #pragma unroll
    for (int ni = 0; ni < 4; ++ni) {
        const int colbase = bn + ni * 16 + g * 4;
        const float4 bv = (colbase < split)
            ? *(const float4*)(bias0 + colbase)
            : *(const float4*)(bias1 + (colbase - split));
        #pragma unroll
        for (int mi = 0; mi < 4; ++mi) {
            const int row = bm + mi * 16 + lr;
            if (row >= M) continue;
            float v0 = acc[mi][ni][0] + bv.x;
            float v1 = acc[mi][ni][1] + bv.y;
            float v2 = acc[mi][ni][2] + bv.z;
            float v3 = acc[mi][ni][3] + bv.w;
            if (RELU) {
                v0 = fmaxf(v0, 0.f); v1 = fmaxf(v1, 0.f);
                v2 = fmaxf(v2, 0.f); v3 = fmaxf(v3, 0.f);
            }
            ushort4 o = { f2b(v0), f2b(v1), f2b(v2), f2b(v3) };
            *(ushort4*)(C + (size_t)row * N + colbase) = o;
        }
    }
}

// ----------------------------- CSR build (by dst) --------------------------
__global__ void hist_kernel(const int* __restrict__ dst, int E, int* __restrict__ hist) {
    int e = blockIdx.x * 256 + threadIdx.x;
    if (e < E) atomicAdd(&hist[dst[e]], 1);
}

// 3-phase parallel exclusive scan of hist[n] -> row_ptr[n+1] (+cursor copy)
__global__ void blk_sum_kernel(const int* __restrict__ hist, int n, int* __restrict__ bsum) {
    __shared__ int lds[256];
    int t = threadIdx.x;
    int i = blockIdx.x * 256 + t;
    lds[t] = (i < n) ? hist[i] : 0;
    __syncthreads();
    for (int off = 128; off > 0; off >>= 1) {
        if (t < off) lds[t] += lds[t + off];
        __syncthreads();
    }
    if (t == 0) bsum[blockIdx.x] = lds[0];
}
__global__ void bsum_scan_kernel(int* __restrict__ bsum, int nblk,
                                 int* __restrict__ row_ptr, int n) {
    __shared__ int lds[256];
    int t = threadIdx.x;
    int v = (t < nblk) ? bsum[t] : 0;
    lds[t] = v;
    __syncthreads();
    for (int off = 1; off < 256; off <<= 1) {
        int u = (t >= off) ? lds[t - off] : 0;
        __syncthreads();
        lds[t] += u;
        __syncthreads();
    }
    if (t < nblk) bsum[t] = lds[t] - v;        // exclusive block offset
    if (t == 255) row_ptr[n] = lds[255];       // grand total
}
__global__ void final_scan_kernel(const int* __restrict__ hist, const int* __restrict__ bsum,
                                  int n, int* __restrict__ row_ptr, int* __restrict__ cursor) {
    __shared__ int lds[256];
    int t = threadIdx.x;
    int i = blockIdx.x * 256 + t;
    int v = (i < n) ? hist[i] : 0;
    lds[t] = v;
    __syncthreads();
    for (int off = 1; off < 256; off <<= 1) {
        int u = (t >= off) ? lds[t - off] : 0;
        __syncthreads();
        lds[t] += u;
        __syncthreads();
    }
    if (i < n) {
        int ex = bsum[blockIdx.x] + lds[t] - v;
        row_ptr[i] = ex;
        cursor[i] = ex;
    }
}

__global__ void scatter_kernel(const int* __restrict__ src, const int* __restrict__ dst,
                               int E, int* cursor, int* __restrict__ esrc)
{
    int e = blockIdx.x * 256 + threadIdx.x;
    if (e < E) {
        int pos = atomicAdd(&cursor[dst[e]], 1);
        esrc[pos] = src[e];
    }
}

// --------------------- fused GATv2 softmax + aggregation -------------------
// One wave per node, TWO edges per wave iteration: half-wave h processes
// virtual edge 2k+h (edge 0 = self loop). Lane sub=lane&31 owns channels
// [8*sub, 8*sub+8) (16B uint4 gather). Online softmax in exp2 domain with
// defer-max; halves merged via shfl_xor(32) on the scale-invariant
// (m, s*2^m) representation. Output written as packed bf16.
template<int CTRL>
__device__ __forceinline__ float dppadd(float v) {
    return v + __int_as_float(__builtin_amdgcn_update_dpp(
        0, __float_as_int(v), CTRL, 0xf, 0xf, true));
}
__device__ __forceinline__ float red8(float v) {
    v = dppadd<0xB1>(v);    // quad_perm xor 1
    v = dppadd<0x4E>(v);    // quad_perm xor 2
    v = dppadd<0x141>(v);   // row_half_mirror
    return v;
}
__device__ __forceinline__ f32x4 unpA(uint4 u) {   // even channels (exact)
    f32x4 r;
    r.x = __uint_as_float(u.x << 16); r.y = __uint_as_float(u.y << 16);
    r.z = __uint_as_float(u.z << 16); r.w = __uint_as_float(u.w << 16);
    return r;
}
__device__ __forceinline__ f32x4 unpB(uint4 u) {   // odd channels (exact)
    f32x4 r;
    r.x = __uint_as_float(u.x & 0xffff0000u); r.y = __uint_as_float(u.y & 0xffff0000u);
    r.z = __uint_as_float(u.z & 0xffff0000u); r.w = __uint_as_float(u.w & 0xffff0000u);
    return r;
}

__global__ __launch_bounds__(256) void gat_aggregate(
    const unsigned short* __restrict__ xlr, const float* __restrict__ att,
    const int* __restrict__ row_ptr, const int* __restrict__ esrc,
    const float* __restrict__ bias, unsigned short* __restrict__ out, int n)
{
    const int lane = threadIdx.x & 63;
    const int node = __builtin_amdgcn_readfirstlane(blockIdx.x * 4 + (threadIdx.x >> 6));
    if (node >= n) return;
    const int sub = lane & 31;
    const int half = lane >> 5;
    const int c8 = sub * 8;

    const float LOG2E = 1.4426950408889634f;
    const float4 a0 = *(const float4*)(att + c8);
    const float4 a1 = *(const float4*)(att + c8 + 4);
    f32x4 attA = { a0.x, a0.z, a1.x, a1.z };   // even channels
    f32x4 attB = { a0.y, a0.w, a1.y, a1.w };   // odd channels
    attA *= LOG2E; attB *= LOG2E;

    const uint4 xru = *(const uint4*)(xlr + (size_t)node * 512 + 256 + c8);
    const f32x4 xrA = unpA(xru), xrB = unpB(xru);

    float m = -1e30f, s = 0.f;
    f32x4 accA = {}, accB = {};

    const int start = row_ptr[node];
    const int cnt = row_ptr[node + 1] - start + 1;   // raw edges + self
    const int kmax = (cnt + 1) >> 1;

    int idx = half;                                   // virtual edge index
    int srcv = (idx == 0) ? node : ((idx < cnt) ? esrc[start + idx - 1] : node);
    uint4 nu = *(const uint4*)(xlr + (size_t)srcv * 512 + c8);

    for (int k = 0; k < kmax; ++k) {
        const f32x4 vA = unpA(nu), vB = unpB(nu);
        const float mask = (idx < cnt) ? 1.f : 0.f;
        const int idxn = idx + 2;
        const int srcn = (idxn < cnt) ? esrc[start + idxn - 1] : node;
        nu = *(const uint4*)(xlr + (size_t)srcn * 512 + c8);   // prefetch

        // score: e = sum_c att[c] * lrelu(xl[src][c] + xr[dst][c])
        const f32x4 zA = vA + xrA, zB = vB + xrB;
        const f32x4 tA = __builtin_elementwise_max(zA, zA * 0.2f);
        const f32x4 tB = __builtin_elementwise_max(zB, zB * 0.2f);
        f32x4 p = attA * tA;
        p = __builtin_elementwise_fma(attB, tB, p);
        const float e = red8((p.x + p.z) + (p.y + p.w));

        const float d = e - m;
        if (__builtin_expect(__any(d > 8.f), 0)) {
            const float mn = fmaxf(m, e);
            const float cs = __builtin_amdgcn_exp2f(m - mn);
            const float w  = __builtin_amdgcn_exp2f(e - mn) * mask;
            s = fmaf(s, cs, w);
            const f32x4 w4 = { w, w, w, w }, cv = { cs, cs, cs, cs };
            accA = __builtin_elementwise_fma(accA, cv, w4 * vA);
            accB = __builtin_elementwise_fma(accB, cv, w4 * vB);
            m = mn;
        } else {
            const float w = __builtin_amdgcn_exp2f(d) * mask;
            s += w;
            const f32x4 w4 = { w, w, w, w };
            accA = __builtin_elementwise_fma(w4, vA, accA);
            accB = __builtin_elementwise_fma(w4, vB, accB);
        }
        idx = idxn;
    }

    // merge the two half-wave states (scale-invariant representation)
    const float m_o = __shfl_xor(m, 32);
    const float s_o = __shfl_xor(s, 32);
    f32x4 accAo, accBo;
    accAo.x = __shfl_xor(accA.x, 32); accAo.y = __shfl_xor(accA.y, 32);
    accAo.z = __shfl_xor(accA.z, 32); accAo.w = __shfl_xor(accA.w, 32);
    accBo.x = __shfl_xor(accB.x, 32); accBo.y = __shfl_xor(accB.y, 32);
    accBo.z = __shfl_xor(accB.z, 32); accBo.w = __shfl_xor(accB.w, 32);
    const float mn = fmaxf(m, m_o);
    const float c0 = __builtin_amdgcn_exp2f(m - mn);
    const float c1 = __builtin_amdgcn_exp2f(m_o - mn);
    const float st = s * c0 + s_o * c1;
    const float inv = 1.f / (st + 1e-16f);

    if (half == 0) {
        const f32x4 oA = (accA * c0 + accAo * c1) * inv;
        const f32x4 oB = (accB * c0 + accBo * c1) * inv;
        const float4 b0 = *(const float4*)(bias + c8);
        const float4 b1 = *(const float4*)(bias + c8 + 4);
        uint4 o;
        o.x = (unsigned)f2b(oA.x + b0.x) | ((unsigned)f2b(oB.x + b0.y) << 16);
        o.y = (unsigned)f2b(oA.y + b0.z) | ((unsigned)f2b(oB.y + b0.w) << 16);
        o.z = (unsigned)f2b(oA.z + b1.x) | ((unsigned)f2b(oB.z + b1.y) << 16);
        o.w = (unsigned)f2b(oA.w + b1.z) | ((unsigned)f2b(oB.w + b1.w) << 16);
        *(uint4*)(out + (size_t)node * 256 + c8) = o;
    }
}

// ------------------- GraphNorm stats + finalize (fused) --------------------
// Per-block column partials -> global atomics; last block (device-scope
// counter) computes the affine coefficients a,c and resets sums/counter.
__global__ __launch_bounds__(256) void colstats_fused(
    const unsigned short* __restrict__ x, int n,
    float* __restrict__ sum, float* __restrict__ sumsq,
    const float* __restrict__ w, const float* __restrict__ b,
    const float* __restrict__ ms,
    float* __restrict__ a, float* __restrict__ c2, float invn,
    int* __restrict__ counter)
{
    const int c = threadIdx.x;
    float s = 0.f, q = 0.f;
    for (int r = blockIdx.x; r < n; r += gridDim.x) {
        float v = __uint_as_float(((unsigned)x[(size_t)r * 256 + c]) << 16);
        s += v;
        q = fmaf(v, v, q);
    }
    atomicAdd(&sum[c], s);
    atomicAdd(&sumsq[c], q);
    __threadfence();
    __shared__ int lastf;
    if (c == 0) lastf = (atomicAdd(counter, 1) == (int)gridDim.x - 1) ? 1 : 0;
    __syncthreads();
    if (lastf) {
        const float sm = atomicAdd(&sum[c], 0.f);    // coherent read-back
        const float sq = atomicAdd(&sumsq[c], 0.f);
        const float mean = sm * invn;
        const float ex2 = sq * invn;
        const float m = ms[c];
        const float var = ex2 - 2.f * m * mean * mean + m * m * mean * mean;
        const float av = w[c] * rsqrtf(var + 1e-5f);
        a[c] = av;
        c2[c] = b[c] - av * m * mean;
        sum[c] = 0.f;                                 // reset for next stage
        sumsq[c] = 0.f;
        if (c == 0) *counter = 0;
    }
}

// in-place normalize + relu on bf16 buffer (8 channels per thread)
__global__ void norm_apply_bf16(unsigned short* __restrict__ x, const float* __restrict__ a,
                                const float* __restrict__ c2, int n8)
{
    int i = blockIdx.x * 256 + threadIdx.x;
    if (i >= n8) return;
    uint4 u = ((uint4*)x)[i];
    const int base = (i * 8) & 255;
    const unsigned uu[4] = { u.x, u.y, u.z, u.w };
    unsigned rr[4];
    #pragma unroll
    for (int j = 0; j < 4; ++j) {
        float lo = __uint_as_float(uu[j] << 16);
        float hi = __uint_as_float(uu[j] & 0xffff0000u);
        lo = fmaxf(fmaf(a[base + 2 * j],     lo, c2[base + 2 * j]),     0.f);
        hi = fmaxf(fmaf(a[base + 2 * j + 1], hi, c2[base + 2 * j + 1]), 0.f);
        rr[j] = (unsigned)f2b(lo) | ((unsigned)f2b(hi) << 16);
    }
    uint4 o = { rr[0], rr[1], rr[2], rr[3] };
    ((uint4*)x)[i] = o;
}

// ---------------------------------- lin2 -----------------------------------
__global__ void lin2_kernel(const unsigned short* __restrict__ h, const float* __restrict__ w,
                            const float* __restrict__ b, float* __restrict__ out, int n)
{
    int i = blockIdx.x * 256 + threadIdx.x;
    if (i >= n) return;
    float a0 = b[0], a1 = b[1];
    const unsigned short* hr = h + (size_t)i * 64;
    #pragma unroll
    for (int k = 0; k < 64; ++k) {
        float v = __uint_as_float(((unsigned)hr[k]) << 16);
        a0 = fmaf(v, w[k * 2 + 0], a0);
        a1 = fmaf(v, w[k * 2 + 1], a1);
    }
    out[i * 2 + 0] = a0;
    out[i * 2 + 1] = a1;
}

// ---------------------------------------------------------------------------
extern "C" void kernel_launch(void* const* d_in, const int* in_sizes, int n_in,
                              void* d_out, int out_size, void* d_ws, size_t ws_size,
                              hipStream_t stream)
{
    const float* x      = (const float*)d_in[0];
    const int*   eidx   = (const int*)d_in[1];
    const float* c0_wl  = (const float*)d_in[2];
    const float* c0_bl  = (const float*)d_in[3];
    const float* c0_wr  = (const float*)d_in[4];
    const float* c0_br  = (const float*)d_in[5];
    const float* c0_att = (const float*)d_in[6];
    const float* c0_bias= (const float*)d_in[7];
    const float* c1_wl  = (const float*)d_in[8];
    const float* c1_bl  = (const float*)d_in[9];
    const float* c1_wr  = (const float*)d_in[10];
    const float* c1_br  = (const float*)d_in[11];
    const float* c1_att = (const float*)d_in[12];
    const float* c1_bias= (const float*)d_in[13];
    const float* gn0_w  = (const float*)d_in[14];
    const float* gn0_b  = (const float*)d_in[15];
    const float* gn0_ms = (const float*)d_in[16];
    const float* gn1_w  = (const float*)d_in[17];
    const float* gn1_b  = (const float*)d_in[18];
    const float* gn1_ms = (const float*)d_in[19];
    const float* lin0_w = (const float*)d_in[20];
    const float* lin0_b = (const float*)d_in[21];
    const float* lin1_w = (const float*)d_in[22];
    const float* lin1_b = (const float*)d_in[23];
    const float* lin2_w = (const float*)d_in[24];
    const float* lin2_b = (const float*)d_in[25];

    const int n = in_sizes[0] / 128;   // 50000
    const int E = in_sizes[1] / 2;     // 800000
    const int* src = eidx;
    const int* dst = eidx + E;

    char* wsp = (char*)d_ws;
    size_t off = 0;
    auto alloc = [&](size_t bytes) -> void* {
        void* p = wsp + off;
        off = (off + bytes + 255) & ~(size_t)255;
        return p;
    };
    unsigned short* xbf  = (unsigned short*)alloc((size_t)n * 128 * 2);  // x bf16
    unsigned short* xlr  = (unsigned short*)alloc((size_t)n * 512 * 2);  // [xl|xr] bf16
    unsigned short* hbB  = (unsigned short*)alloc((size_t)n * 256 * 2);  // conv out bf16 (in-place norm)
    unsigned short* mbuf = (unsigned short*)alloc((size_t)n * 64 * 2);
    unsigned short* mbuf2= (unsigned short*)alloc((size_t)n * 64 * 2);
    unsigned short* Wt0  = (unsigned short*)alloc((size_t)512 * 128 * 2);
    unsigned short* Wt1  = (unsigned short*)alloc((size_t)512 * 256 * 2);
    unsigned short* Lt0  = (unsigned short*)alloc((size_t)64 * 256 * 2);
    unsigned short* Lt1  = (unsigned short*)alloc((size_t)64 * 64 * 2);
    int*   esrc    = (int*)alloc((size_t)E * 4);
    int*   row_ptr = (int*)alloc((size_t)(n + 1) * 4);
    int*   cursor  = (int*)alloc((size_t)n * 4);
    int*   hist    = (int*)alloc((size_t)n * 4);
    int*   bsum    = (int*)alloc((size_t)256 * 4);
    float* s_sum   = (float*)alloc(256 * 4);   // contiguous: s_sum, s_sq
    float* s_sq    = (float*)alloc(256 * 4);
    float* s_a     = (float*)alloc(256 * 4);
    float* s_c     = (float*)alloc(256 * 4);
    int*   counter = (int*)alloc(256);

    // ---- fused prep: zero(s_sum,s_sq,counter,hist) + cast + 6 transposes ----
    const int nx4 = n * 128 / 4;                       // 1.6M
    const int prep_total = 512 + n + nx4 + 32768 * 2 + 65536 * 2 + 16384 + 4096;
    prep_all<<<(prep_total + 255) / 256, 256, 0, stream>>>(
        x, xbf, nx4, c0_wl, c0_wr, Wt0, c1_wl, c1_wr, Wt1,
        lin0_w, Lt0, lin1_w, Lt1, s_sum, hist, n, counter);

    // ---- CSR by dst (parallel scan) ----
    const int nblk = (n + 255) / 256;   // 196 <= 256
    hist_kernel<<<(E + 255) / 256, 256, 0, stream>>>(dst, E, hist);
    blk_sum_kernel<<<nblk, 256, 0, stream>>>(hist, n, bsum);
    bsum_scan_kernel<<<1, 256, 0, stream>>>(bsum, nblk, row_ptr, n);
    final_scan_kernel<<<nblk, 256, 0, stream>>>(hist, bsum, n, row_ptr, cursor);
    scatter_kernel<<<(E + 255) / 256, 256, 0, stream>>>(src, dst, E, cursor, esrc);

    const int mt = (n + 255) / 256;     // 196 M-tiles (256 rows each)
    const int gagg = (n + 3) / 4;

    // ---- conv0: fused [xl|xr] GEMM + aggregate + norm (bf16 in-place) ----
    mfma_gemm<128, false><<<mt * 8, 256, 0, stream>>>(xbf, Wt0, c0_bl, c0_br, 256, xlr, n, 512, 8);
    gat_aggregate<<<gagg, 256, 0, stream>>>(xlr, c0_att, row_ptr, esrc, c0_bias, hbB, n);
    colstats_fused<<<512, 256, 0, stream>>>(hbB, n, s_sum, s_sq, gn0_w, gn0_b, gn0_ms,
                                            s_a, s_c, 1.f / n, counter);
    norm_apply_bf16<<<((n * 32) + 255) / 256, 256, 0, stream>>>(hbB, s_a, s_c, n * 32);

    // ---- conv1 ----
    mfma_gemm<256, false><<<mt * 8, 256, 0, stream>>>(hbB, Wt1, c1_bl, c1_br, 256, xlr, n, 512, 8);
    gat_aggregate<<<gagg, 256, 0, stream>>>(xlr, c1_att, row_ptr, esrc, c1_bias, hbB, n);
    colstats_fused<<<512, 256, 0, stream>>>(hbB, n, s_sum, s_sq, gn1_w, gn1_b, gn1_ms,
                                            s_a, s_c, 1.f / n, counter);
    norm_apply_bf16<<<((n * 32) + 255) / 256, 256, 0, stream>>>(hbB, s_a, s_c, n * 32);

    // ---- MLP ----
    mfma_gemm<256, true><<<mt, 256, 0, stream>>>(hbB, Lt0, lin0_b, lin0_b, 64, mbuf, n, 64, 1);
    mfma_gemm<64, true><<<mt, 256, 0, stream>>>(mbuf, Lt1, lin1_b, lin1_b, 64, mbuf2, n, 64, 1);
    lin2_kernel<<<(n + 255) / 256, 256, 0, stream>>>(mbuf2, lin2_w, lin2_b, (float*)d_out, n);
}

// Round 13
// 436.404 us; speedup vs baseline: 1.1477x; 1.1477x over previous
//
#include <hip/hip_runtime.h>
#include <hip/hip_bf16.h>

// ---------------------------------------------------------------------------
// GATv2 (2 conv + GraphNorm + MLP) on MI355X.
// Round 13: GEMM epilogue staged through LDS -> full-sector coalesced C
// stores (fixes 2x write amplification seen in r12 counters: WRITE 101MB for
// a 51MB output, HBM 1.7TB/s). Revert colstats fusion (r12 regression);
// keep prep_all. Aggregate unchanged (at its latency floor ~69us).
// ---------------------------------------------------------------------------

typedef __bf16 bf16x8 __attribute__((ext_vector_type(8)));
typedef float  f32x4  __attribute__((ext_vector_type(4)));

__device__ __forceinline__ unsigned short f2b(float f) {   // RNE f32->bf16
    unsigned u = __float_as_uint(f);
    return (unsigned short)((u + 0x7fffu + ((u >> 16) & 1u)) >> 16);
}

// ----------------------------- fused prep ----------------------------------
// Segments: [zero s_sum/s_sq (512 f)] [zero hist (n i32)] [cast x (nx4 u4)]
// [T c0_wl 32768] [T c0_wr 32768] [T c1_wl 65536] [T c1_wr 65536]
// [T lin0 16384] [T lin1 4096]
__global__ __launch_bounds__(256) void prep_all(
    const float* __restrict__ x, unsigned short* __restrict__ xbf, int nx4,
    const float* __restrict__ w0l, const float* __restrict__ w0r, unsigned short* __restrict__ Wt0,
    const float* __restrict__ w1l, const float* __restrict__ w1r, unsigned short* __restrict__ Wt1,
    const float* __restrict__ l0, unsigned short* __restrict__ Lt0,
    const float* __restrict__ l1, unsigned short* __restrict__ Lt1,
    float* __restrict__ zf, int* __restrict__ hist, int nh)
{
    int t = blockIdx.x * 256 + threadIdx.x;
    if (t < 512) { zf[t] = 0.f; }
    int i = t - 512;
    if (i >= 0 && i < nh) hist[i] = 0;
    i -= nh;
    if (i >= 0 && i < nx4) {
        float4 v = ((const float4*)x)[i];
        ushort4 o = { f2b(v.x), f2b(v.y), f2b(v.z), f2b(v.w) };
        ((ushort4*)xbf)[i] = o;
    }
    i -= nx4;
    if (i >= 0 && i < 32768) { int nn = i >> 7, kk = i & 127; Wt0[i] = f2b(w0l[kk * 256 + nn]); }
    i -= 32768;
    if (i >= 0 && i < 32768) { int nn = i >> 7, kk = i & 127; Wt0[32768 + i] = f2b(w0r[kk * 256 + nn]); }
    i -= 32768;
    if (i >= 0 && i < 65536) { int nn = i >> 8, kk = i & 255; Wt1[i] = f2b(w1l[kk * 256 + nn]); }
    i -= 65536;
    if (i >= 0 && i < 65536) { int nn = i >> 8, kk = i & 255; Wt1[65536 + i] = f2b(w1r[kk * 256 + nn]); }
    i -= 65536;
    if (i >= 0 && i < 16384) { int nn = i >> 8, kk = i & 255; Lt0[i] = f2b(l0[kk * 64 + nn]); }
    i -= 16384;
    if (i >= 0 && i < 4096)  { int nn = i >> 6, kk = i & 63;  Lt1[i] = f2b(l1[kk * 64 + nn]); }
}

// ----------------------------- MFMA GEMM -----------------------------------
// C[M,N](bf16) = act(A[M,K](bf16) @ Bt[N,K]^T(bf16) + bias); K compile-time.
// Block: 4 waves, tile 256(M)x64(N); wave w owns rows [w*64, w*64+64).
// Epilogue stages the C tile in LDS, then streams full-sector 16B/lane
// stores (fixes the 2x partial-sector write amplification).
template<int K, bool RELU>
__global__ __launch_bounds__(256) void mfma_gemm(
    const unsigned short* __restrict__ A, const unsigned short* __restrict__ Bt,
    const float* __restrict__ bias0, const float* __restrict__ bias1, int split,
    unsigned short* __restrict__ C, int M, int N, int nt)
{
    __shared__ unsigned short cs[256][72];   // 36KB; row stride 144B (16B-aligned)

    // XCD-bijective swizzle of flat block id (m204 formula)
    const int nwg = gridDim.x;
    const int bid = blockIdx.x;
    const int q = nwg >> 3, r = nwg & 7;
    const int xcd = bid & 7, pos = bid >> 3;
    const int wgid = (xcd < r ? xcd * (q + 1) : r * (q + 1) + (xcd - r) * q) + pos;
    const int tm = wgid / nt;            // M-tile (flat is M-fast within chunk)
    const int tn = wgid - tm * nt;       // N-tile

    const int lane = threadIdx.x & 63;
    const int w = threadIdx.x >> 6;
    const int bm = tm * 256 + w * 64;
    const int bn = tn * 64;
    const int lr = lane & 15;
    const int g  = lane >> 4;
    const int lk = g * 8;

    f32x4 acc[4][4] = {};
    const unsigned short* pa[4];
    #pragma unroll
    for (int mi = 0; mi < 4; ++mi) {
        int rr = bm + mi * 16 + lr;
        if (rr >= M) rr = M - 1;         // clamp (writes are guarded)
        pa[mi] = A + (size_t)rr * K + lk;
    }
    const unsigned short* pb = Bt + (size_t)(bn + lr) * K + lk;

    #pragma unroll
    for (int k0 = 0; k0 < K; k0 += 32) {
        bf16x8 bfr[4], afr[4];
        #pragma unroll
        for (int ni = 0; ni < 4; ++ni)
            bfr[ni] = *(const bf16x8*)(pb + (size_t)ni * 16 * K + k0);
        #pragma unroll
        for (int mi = 0; mi < 4; ++mi)
            afr[mi] = *(const bf16x8*)(pa[mi] + k0);
        #pragma unroll
        for (int mi = 0; mi < 4; ++mi)
            #pragma unroll
            for (int ni = 0; ni < 4; ++ni)
                acc[mi][ni] = __builtin_amdgcn_mfma_f32_16x16x32_bf16(
                    bfr[ni], afr[mi], acc[mi][ni], 0, 0, 0);
    }

    // stage: lane holds C[bm+mi*16+lr][bn+ni*16+g*4 .. +3] -> LDS
    #pragma unroll
    for (int ni = 0; ni < 4; ++ni) {
        const int colbase = bn + ni * 16 + g * 4;
        const float4 bv = (colbase < split)
            ? *(const float4*)(bias0 + colbase)
            : *(const float4*)(bias1 + (colbase - split));
        #pragma unroll
        for (int mi = 0; mi < 4; ++mi) {
            float v0 = acc[mi][ni][0] + bv.x;
            float v1 = acc[mi][ni][1] + bv.y;
            float v2 = acc[mi][ni][2] + bv.z;
            float v3 = acc[mi][ni][3] + bv.w;
            if (RELU) {
                v0 = fmaxf(v0, 0.f); v1 = fmaxf(v1, 0.f);
                v2 = fmaxf(v2, 0.f); v3 = fmaxf(v3, 0.f);
            }
            ushort4 o = { f2b(v0), f2b(v1), f2b(v2), f2b(v3) };
            *(ushort4*)&cs[w * 64 + mi * 16 + lr][ni * 16 + g * 4] = o;
        }
    }
    __syncthreads();

    // stream out: 8 passes x (32 rows x 8 segs of 16B) = full sectors
    const int row32 = threadIdx.x >> 3;
    const int seg = threadIdx.x & 7;
    #pragma unroll
    for (int p = 0; p < 8; ++p) {
        const int lrow = p * 32 + row32;
        const int grow = tm * 256 + lrow;
        if (grow < M)
            *(uint4*)(C + (size_t)grow * N + bn + seg * 8) =
                *(const uint4*)&cs[lrow][seg * 8];
    }
}

// ----------------------------- CSR build (by dst) --------------------------
__global__ void zero_f32(float* __restrict__ p, int n) {
    int i = blockIdx.x * 256 + threadIdx.x;
    if (i < n) p[i] = 0.f;
}
__global__ void hist_kernel(const int* __restrict__ dst, int E, int* __restrict__ hist) {
    int e = blockIdx.x * 256 + threadIdx.x;
    if (e < E) atomicAdd(&hist[dst[e]], 1);
}

// 3-phase parallel exclusive scan of hist[n] -> row_ptr[n+1] (+cursor copy)
__global__ void blk_sum_kernel(const int* __restrict__ hist, int n, int* __restrict__ bsum) {
    __shared__ int lds[256];
    int t = threadIdx.x;
    int i = blockIdx.x * 256 + t;
    lds[t] = (i < n) ? hist[i] : 0;
    __syncthreads();
    for (int off = 128; off > 0; off >>= 1) {
        if (t < off) lds[t] += lds[t + off];
        __syncthreads();
    }
    if (t == 0) bsum[blockIdx.x] = lds[0];
}
__global__ void bsum_scan_kernel(int* __restrict__ bsum, int nblk,
                                 int* __restrict__ row_ptr, int n) {
    __shared__ int lds[256];
    int t = threadIdx.x;
    int v = (t < nblk) ? bsum[t] : 0;
    lds[t] = v;
    __syncthreads();
    for (int off = 1; off < 256; off <<= 1) {
        int u = (t >= off) ? lds[t - off] : 0;
        __syncthreads();
        lds[t] += u;
        __syncthreads();
    }
    if (t < nblk) bsum[t] = lds[t] - v;        // exclusive block offset
    if (t == 255) row_ptr[n] = lds[255];       // grand total
}
__global__ void final_scan_kernel(const int* __restrict__ hist, const int* __restrict__ bsum,
                                  int n, int* __restrict__ row_ptr, int* __restrict__ cursor) {
    __shared__ int lds[256];
    int t = threadIdx.x;
    int i = blockIdx.x * 256 + t;
    int v = (i < n) ? hist[i] : 0;
    lds[t] = v;
    __syncthreads();
    for (int off = 1; off < 256; off <<= 1) {
        int u = (t >= off) ? lds[t - off] : 0;
        __syncthreads();
        lds[t] += u;
        __syncthreads();
    }
    if (i < n) {
        int ex = bsum[blockIdx.x] + lds[t] - v;
        row_ptr[i] = ex;
        cursor[i] = ex;
    }
}

__global__ void scatter_kernel(const int* __restrict__ src, const int* __restrict__ dst,
                               int E, int* cursor, int* __restrict__ esrc)
{
    int e = blockIdx.x * 256 + threadIdx.x;
    if (e < E) {
        int pos = atomicAdd(&cursor[dst[e]], 1);
        esrc[pos] = src[e];
    }
}

// --------------------- fused GATv2 softmax + aggregation -------------------
// One wave per node, TWO edges per wave iteration: half-wave h processes
// virtual edge 2k+h (edge 0 = self loop). Lane sub=lane&31 owns channels
// [8*sub, 8*sub+8) (16B uint4 gather). Online softmax in exp2 domain with
// defer-max; halves merged via shfl_xor(32) on the scale-invariant
// (m, s*2^m) representation. Output written as packed bf16.
template<int CTRL>
__device__ __forceinline__ float dppadd(float v) {
    return v + __int_as_float(__builtin_amdgcn_update_dpp(
        0, __float_as_int(v), CTRL, 0xf, 0xf, true));
}
__device__ __forceinline__ float red8(float v) {
    v = dppadd<0xB1>(v);    // quad_perm xor 1
    v = dppadd<0x4E>(v);    // quad_perm xor 2
    v = dppadd<0x141>(v);   // row_half_mirror
    return v;
}
__device__ __forceinline__ f32x4 unpA(uint4 u) {   // even channels (exact)
    f32x4 r;
    r.x = __uint_as_float(u.x << 16); r.y = __uint_as_float(u.y << 16);
    r.z = __uint_as_float(u.z << 16); r.w = __uint_as_float(u.w << 16);
    return r;
}
__device__ __forceinline__ f32x4 unpB(uint4 u) {   // odd channels (exact)
    f32x4 r;
    r.x = __uint_as_float(u.x & 0xffff0000u); r.y = __uint_as_float(u.y & 0xffff0000u);
    r.z = __uint_as_float(u.z & 0xffff0000u); r.w = __uint_as_float(u.w & 0xffff0000u);
    return r;
}

__global__ __launch_bounds__(256) void gat_aggregate(
    const unsigned short* __restrict__ xlr, const float* __restrict__ att,
    const int* __restrict__ row_ptr, const int* __restrict__ esrc,
    const float* __restrict__ bias, unsigned short* __restrict__ out, int n)
{
    const int lane = threadIdx.x & 63;
    const int node = __builtin_amdgcn_readfirstlane(blockIdx.x * 4 + (threadIdx.x >> 6));
    if (node >= n) return;
    const int sub = lane & 31;
    const int half = lane >> 5;
    const int c8 = sub * 8;

    const float LOG2E = 1.4426950408889634f;
    const float4 a0 = *(const float4*)(att + c8);
    const float4 a1 = *(const float4*)(att + c8 + 4);
    f32x4 attA = { a0.x, a0.z, a1.x, a1.z };   // even channels
    f32x4 attB = { a0.y, a0.w, a1.y, a1.w };   // odd channels
    attA *= LOG2E; attB *= LOG2E;

    const uint4 xru = *(const uint4*)(xlr + (size_t)node * 512 + 256 + c8);
    const f32x4 xrA = unpA(xru), xrB = unpB(xru);

    float m = -1e30f, s = 0.f;
    f32x4 accA = {}, accB = {};

    const int start = row_ptr[node];
    const int cnt = row_ptr[node + 1] - start + 1;   // raw edges + self
    const int kmax = (cnt + 1) >> 1;

    int idx = half;                                   // virtual edge index
    int srcv = (idx == 0) ? node : ((idx < cnt) ? esrc[start + idx - 1] : node);
    uint4 nu = *(const uint4*)(xlr + (size_t)srcv * 512 + c8);

    for (int k = 0; k < kmax; ++k) {
        const f32x4 vA = unpA(nu), vB = unpB(nu);
        const float mask = (idx < cnt) ? 1.f : 0.f;
        const int idxn = idx + 2;
        const int srcn = (idxn < cnt) ? esrc[start + idxn - 1] : node;
        nu = *(const uint4*)(xlr + (size_t)srcn * 512 + c8);   // prefetch

        // score: e = sum_c att[c] * lrelu(xl[src][c] + xr[dst][c])
        const f32x4 zA = vA + xrA, zB = vB + xrB;
        const f32x4 tA = __builtin_elementwise_max(zA, zA * 0.2f);
        const f32x4 tB = __builtin_elementwise_max(zB, zB * 0.2f);
        f32x4 p = attA * tA;
        p = __builtin_elementwise_fma(attB, tB, p);
        const float e = red8((p.x + p.z) + (p.y + p.w));

        const float d = e - m;
        if (__builtin_expect(__any(d > 8.f), 0)) {
            const float mn = fmaxf(m, e);
            const float cs = __builtin_amdgcn_exp2f(m - mn);
            const float w  = __builtin_amdgcn_exp2f(e - mn) * mask;
            s = fmaf(s, cs, w);
            const f32x4 w4 = { w, w, w, w }, cv = { cs, cs, cs, cs };
            accA = __builtin_elementwise_fma(accA, cv, w4 * vA);
            accB = __builtin_elementwise_fma(accB, cv, w4 * vB);
            m = mn;
        } else {
            const float w = __builtin_amdgcn_exp2f(d) * mask;
            s += w;
            const f32x4 w4 = { w, w, w, w };
            accA = __builtin_elementwise_fma(w4, vA, accA);
            accB = __builtin_elementwise_fma(w4, vB, accB);
        }
        idx = idxn;
    }

    // merge the two half-wave states (scale-invariant representation)
    const float m_o = __shfl_xor(m, 32);
    const float s_o = __shfl_xor(s, 32);
    f32x4 accAo, accBo;
    accAo.x = __shfl_xor(accA.x, 32); accAo.y = __shfl_xor(accA.y, 32);
    accAo.z = __shfl_xor(accA.z, 32); accAo.w = __shfl_xor(accA.w, 32);
    accBo.x = __shfl_xor(accB.x, 32); accBo.y = __shfl_xor(accB.y, 32);
    accBo.z = __shfl_xor(accB.z, 32); accBo.w = __shfl_xor(accB.w, 32);
    const float mn = fmaxf(m, m_o);
    const float c0 = __builtin_amdgcn_exp2f(m - mn);
    const float c1 = __builtin_amdgcn_exp2f(m_o - mn);
    const float st = s * c0 + s_o * c1;
    const float inv = 1.f / (st + 1e-16f);

    if (half == 0) {
        const f32x4 oA = (accA * c0 + accAo * c1) * inv;
        const f32x4 oB = (accB * c0 + accBo * c1) * inv;
        const float4 b0 = *(const float4*)(bias + c8);
        const float4 b1 = *(const float4*)(bias + c8 + 4);
        uint4 o;
        o.x = (unsigned)f2b(oA.x + b0.x) | ((unsigned)f2b(oB.x + b0.y) << 16);
        o.y = (unsigned)f2b(oA.y + b0.z) | ((unsigned)f2b(oB.y + b0.w) << 16);
        o.z = (unsigned)f2b(oA.z + b1.x) | ((unsigned)f2b(oB.z + b1.y) << 16);
        o.w = (unsigned)f2b(oA.w + b1.z) | ((unsigned)f2b(oB.w + b1.w) << 16);
        *(uint4*)(out + (size_t)node * 256 + c8) = o;
    }
}

// ------------------------------- GraphNorm (bf16) --------------------------
__global__ __launch_bounds__(256) void colstats_bf16(
    const unsigned short* __restrict__ x, int n,
    float* __restrict__ sum, float* __restrict__ sumsq)
{
    const int c = threadIdx.x;
    float s = 0.f, q = 0.f;
    for (int r = blockIdx.x; r < n; r += gridDim.x) {
        float v = __uint_as_float(((unsigned)x[(size_t)r * 256 + c]) << 16);
        s += v;
        q = fmaf(v, v, q);
    }
    atomicAdd(&sum[c], s);
    atomicAdd(&sumsq[c], q);
}
__global__ void norm_finalize(const float* __restrict__ sum, const float* __restrict__ sumsq,
                              const float* __restrict__ w, const float* __restrict__ b,
                              const float* __restrict__ ms,
                              float* __restrict__ a, float* __restrict__ c2, float invn)
{
    int i = threadIdx.x;
    float mean = sum[i] * invn;
    float ex2 = sumsq[i] * invn;
    float m = ms[i];
    float var = ex2 - 2.f * m * mean * mean + m * m * mean * mean;
    float av = w[i] * rsqrtf(var + 1e-5f);
    a[i] = av;
    c2[i] = b[i] - av * m * mean;
}
// in-place normalize + relu on bf16 buffer (8 channels per thread)
__global__ void norm_apply_bf16(unsigned short* __restrict__ x, const float* __restrict__ a,
                                const float* __restrict__ c2, int n8)
{
    int i = blockIdx.x * 256 + threadIdx.x;
    if (i >= n8) return;
    uint4 u = ((uint4*)x)[i];
    const int base = (i * 8) & 255;
    const unsigned uu[4] = { u.x, u.y, u.z, u.w };
    unsigned rr[4];
    #pragma unroll
    for (int j = 0; j < 4; ++j) {
        float lo = __uint_as_float(uu[j] << 16);
        float hi = __uint_as_float(uu[j] & 0xffff0000u);
        lo = fmaxf(fmaf(a[base + 2 * j],     lo, c2[base + 2 * j]),     0.f);
        hi = fmaxf(fmaf(a[base + 2 * j + 1], hi, c2[base + 2 * j + 1]), 0.f);
        rr[j] = (unsigned)f2b(lo) | ((unsigned)f2b(hi) << 16);
    }
    uint4 o = { rr[0], rr[1], rr[2], rr[3] };
    ((uint4*)x)[i] = o;
}

// ---------------------------------- lin2 -----------------------------------
__global__ void lin2_kernel(const unsigned short* __restrict__ h, const float* __restrict__ w,
                            const float* __restrict__ b, float* __restrict__ out, int n)
{
    int i = blockIdx.x * 256 + threadIdx.x;
    if (i >= n) return;
    float a0 = b[0], a1 = b[1];
    const unsigned short* hr = h + (size_t)i * 64;
    #pragma unroll
    for (int k = 0; k < 64; ++k) {
        float v = __uint_as_float(((unsigned)hr[k]) << 16);
        a0 = fmaf(v, w[k * 2 + 0], a0);
        a1 = fmaf(v, w[k * 2 + 1], a1);
    }
    out[i * 2 + 0] = a0;
    out[i * 2 + 1] = a1;
}

// ---------------------------------------------------------------------------
extern "C" void kernel_launch(void* const* d_in, const int* in_sizes, int n_in,
                              void* d_out, int out_size, void* d_ws, size_t ws_size,
                              hipStream_t stream)
{
    const float* x      = (const float*)d_in[0];
    const int*   eidx   = (const int*)d_in[1];
    const float* c0_wl  = (const float*)d_in[2];
    const float* c0_bl  = (const float*)d_in[3];
    const float* c0_wr  = (const float*)d_in[4];
    const float* c0_br  = (const float*)d_in[5];
    const float* c0_att = (const float*)d_in[6];
    const float* c0_bias= (const float*)d_in[7];
    const float* c1_wl  = (const float*)d_in[8];
    const float* c1_bl  = (const float*)d_in[9];
    const float* c1_wr  = (const float*)d_in[10];
    const float* c1_br  = (const float*)d_in[11];
    const float* c1_att = (const float*)d_in[12];
    const float* c1_bias= (const float*)d_in[13];
    const float* gn0_w  = (const float*)d_in[14];
    const float* gn0_b  = (const float*)d_in[15];
    const float* gn0_ms = (const float*)d_in[16];
    const float* gn1_w  = (const float*)d_in[17];
    const float* gn1_b  = (const float*)d_in[18];
    const float* gn1_ms = (const float*)d_in[19];
    const float* lin0_w = (const float*)d_in[20];
    const float* lin0_b = (const float*)d_in[21];
    const float* lin1_w = (const float*)d_in[22];
    const float* lin1_b = (const float*)d_in[23];
    const float* lin2_w = (const float*)d_in[24];
    const float* lin2_b = (const float*)d_in[25];

    const int n = in_sizes[0] / 128;   // 50000
    const int E = in_sizes[1] / 2;     // 800000
    const int* src = eidx;
    const int* dst = eidx + E;

    char* wsp = (char*)d_ws;
    size_t off = 0;
    auto alloc = [&](size_t bytes) -> void* {
        void* p = wsp + off;
        off = (off + bytes + 255) & ~(size_t)255;
        return p;
    };
    unsigned short* xbf  = (unsigned short*)alloc((size_t)n * 128 * 2);  // x bf16
    unsigned short* xlr  = (unsigned short*)alloc((size_t)n * 512 * 2);  // [xl|xr] bf16
    unsigned short* hbB  = (unsigned short*)alloc((size_t)n * 256 * 2);  // conv out bf16 (in-place norm)
    unsigned short* mbuf = (unsigned short*)alloc((size_t)n * 64 * 2);
    unsigned short* mbuf2= (unsigned short*)alloc((size_t)n * 64 * 2);
    unsigned short* Wt0  = (unsigned short*)alloc((size_t)512 * 128 * 2);
    unsigned short* Wt1  = (unsigned short*)alloc((size_t)512 * 256 * 2);
    unsigned short* Lt0  = (unsigned short*)alloc((size_t)64 * 256 * 2);
    unsigned short* Lt1  = (unsigned short*)alloc((size_t)64 * 64 * 2);
    int*   esrc    = (int*)alloc((size_t)E * 4);
    int*   row_ptr = (int*)alloc((size_t)(n + 1) * 4);
    int*   cursor  = (int*)alloc((size_t)n * 4);
    int*   hist    = (int*)alloc((size_t)n * 4);
    int*   bsum    = (int*)alloc((size_t)256 * 4);
    float* s_sum   = (float*)alloc(256 * 4);   // contiguous: s_sum, s_sq
    float* s_sq    = (float*)alloc(256 * 4);
    float* s_a     = (float*)alloc(256 * 4);
    float* s_c     = (float*)alloc(256 * 4);

    // ---- fused prep: zero(s_sum,s_sq,hist) + cast + 6 transposes ----
    const int nx4 = n * 128 / 4;                       // 1.6M
    const int prep_total = 512 + n + nx4 + 32768 * 2 + 65536 * 2 + 16384 + 4096;
    prep_all<<<(prep_total + 255) / 256, 256, 0, stream>>>(
        x, xbf, nx4, c0_wl, c0_wr, Wt0, c1_wl, c1_wr, Wt1,
        lin0_w, Lt0, lin1_w, Lt1, s_sum, hist, n);

    // ---- CSR by dst (parallel scan) ----
    const int nblk = (n + 255) / 256;   // 196 <= 256
    hist_kernel<<<(E + 255) / 256, 256, 0, stream>>>(dst, E, hist);
    blk_sum_kernel<<<nblk, 256, 0, stream>>>(hist, n, bsum);
    bsum_scan_kernel<<<1, 256, 0, stream>>>(bsum, nblk, row_ptr, n);
    final_scan_kernel<<<nblk, 256, 0, stream>>>(hist, bsum, n, row_ptr, cursor);
    scatter_kernel<<<(E + 255) / 256, 256, 0, stream>>>(src, dst, E, cursor, esrc);

    const int mt = (n + 255) / 256;     // 196 M-tiles (256 rows each)
    const int gagg = (n + 3) / 4;

    // ---- conv0: fused [xl|xr] GEMM + aggregate + norm (bf16 in-place) ----
    mfma_gemm<128, false><<<mt * 8, 256, 0, stream>>>(xbf, Wt0, c0_bl, c0_br, 256, xlr, n, 512, 8);
    gat_aggregate<<<gagg, 256, 0, stream>>>(xlr, c0_att, row_ptr, esrc, c0_bias, hbB, n);
    colstats_bf16<<<512, 256, 0, stream>>>(hbB, n, s_sum, s_sq);
    norm_finalize<<<1, 256, 0, stream>>>(s_sum, s_sq, gn0_w, gn0_b, gn0_ms, s_a, s_c, 1.f / n);
    norm_apply_bf16<<<((n * 32) + 255) / 256, 256, 0, stream>>>(hbB, s_a, s_c, n * 32);

    // ---- conv1 ----
    zero_f32<<<2, 256, 0, stream>>>(s_sum, 512);
    mfma_gemm<256, false><<<mt * 8, 256, 0, stream>>>(hbB, Wt1, c1_bl, c1_br, 256, xlr, n, 512, 8);
    gat_aggregate<<<gagg, 256, 0, stream>>>(xlr, c1_att, row_ptr, esrc, c1_bias, hbB, n);
    colstats_bf16<<<512, 256, 0, stream>>>(hbB, n, s_sum, s_sq);
    norm_finalize<<<1, 256, 0, stream>>>(s_sum, s_sq, gn1_w, gn1_b, gn1_ms, s_a, s_c, 1.f / n);
    norm_apply_bf16<<<((n * 32) + 255) / 256, 256, 0, stream>>>(hbB, s_a, s_c, n * 32);

    // ---- MLP ----
    mfma_gemm<256, true><<<mt, 256, 0, stream>>>(hbB, Lt0, lin0_b, lin0_b, 64, mbuf, n, 64, 1);
    mfma_gemm<64, true><<<mt, 256, 0, stream>>>(mbuf, Lt1, lin1_b, lin1_b, 64, mbuf2, n, 64, 1);
    lin2_kernel<<<(n + 255) / 256, 256, 0, stream>>>(mbuf2, lin2_w, lin2_b, (float*)d_out, n);
}